// Round 2
// baseline (1283.279 us; speedup 1.0000x reference)
//
#include <hip/hip_runtime.h>

// FocalLoss: B=8192 rows, V=32000 logits/row, fp32.
// loss = -mean_i (1 - p_i)^2 * logp_i,  logp_i = log_softmax(pred)[i, labels[i]]
//
// Strategy: one wave64 per row, ONLINE softmax (single pass over pred -> 1.05 GB
// HBM traffic, the roofline floor). All math in log2 domain (v_exp_f32/v_log_f32
// are base-2 HW ops). Two (m,s) accumulators per lane for ILP. Wave butterfly
// merge, per-row loss -> d_ws, tiny second kernel does the deterministic mean.
//
// Round 1 was an infra failure (container died before running); this is a retry
// of the same design.

constexpr int B = 8192;
constexpr int V = 32000;                  // = 8000 float4 = 125 float4/lane
constexpr float LOG2E = 1.4426950408889634f;
constexpr float LN2   = 0.6931471805599453f;

__device__ __forceinline__ float fexp2(float x) { return __builtin_amdgcn_exp2f(x); }
__device__ __forceinline__ float flog2(float x) { return __builtin_amdgcn_logf(x); }  // v_log_f32 = log2

__device__ __forceinline__ void upd(float& m, float& s, float4 v) {
    float t0 = v.x * LOG2E, t1 = v.y * LOG2E, t2 = v.z * LOG2E, t3 = v.w * LOG2E;
    float xm = fmaxf(fmaxf(t0, t1), fmaxf(t2, t3));
    float mn = fmaxf(m, xm);
    s = s * fexp2(m - mn)
      + (fexp2(t0 - mn) + fexp2(t1 - mn))
      + (fexp2(t2 - mn) + fexp2(t3 - mn));
    m = mn;
}

__global__ __launch_bounds__(256) void focal_rows(const float* __restrict__ pred,
                                                  const int* __restrict__ labels,
                                                  float* __restrict__ row_loss) {
    const int wave = threadIdx.x >> 6;
    const int lane = threadIdx.x & 63;
    const int row  = (blockIdx.x << 2) + wave;
    const float4* rp4 = (const float4*)(pred + (size_t)row * V);

    // -1e30f (not -INF) avoids inf arithmetic; exp2(-1e30) flushes to 0 in HW.
    float m0 = -1e30f, s0 = 0.f;
    float m1 = -1e30f, s1 = 0.f;

    #pragma unroll 2
    for (int j = 0; j < 62; ++j) {          // 124 float4/lane in pairs
        float4 a = rp4[lane + 128 * j];
        float4 b = rp4[lane + 128 * j + 64];
        upd(m0, s0, a);
        upd(m1, s1, b);
    }
    { float4 a = rp4[lane + 64 * 124]; upd(m0, s0, a); }  // tail (125th)

    // merge the two accumulators
    float m = fmaxf(m0, m1);
    float s = s0 * fexp2(m0 - m) + s1 * fexp2(m1 - m);

    // wave64 butterfly merge of (m, s)
    #pragma unroll
    for (int off = 1; off < 64; off <<= 1) {
        float mo = __shfl_xor(m, off, 64);
        float so = __shfl_xor(s, off, 64);
        float mn = fmaxf(m, mo);
        s = s * fexp2(m - mn) + so * fexp2(mo - mn);
        m = mn;
    }

    if (lane == 0) {
        int lab = labels[row];
        float t     = ((const float*)rp4)[lab] * LOG2E;   // label logit, log2 domain
        float logp2 = t - m - flog2(s);                   // log2 p
        float logp  = logp2 * LN2;                        // ln p
        float p     = fexp2(logp2);
        float om    = 1.f - p;
        row_loss[row] = -om * om * logp;                  // positive contribution
    }
}

__global__ __launch_bounds__(256) void reduce_rows(const float* __restrict__ row_loss,
                                                   float* __restrict__ out) {
    float acc = 0.f;
    #pragma unroll
    for (int i = 0; i < B / 256; ++i)                     // 32 strided loads/thread
        acc += row_loss[threadIdx.x + 256 * i];
    #pragma unroll
    for (int off = 32; off > 0; off >>= 1)
        acc += __shfl_down(acc, off, 64);
    __shared__ float ws[4];
    if ((threadIdx.x & 63) == 0) ws[threadIdx.x >> 6] = acc;
    __syncthreads();
    if (threadIdx.x == 0)
        out[0] = (ws[0] + ws[1] + ws[2] + ws[3]) * (1.0f / (float)B);
}

extern "C" void kernel_launch(void* const* d_in, const int* in_sizes, int n_in,
                              void* d_out, int out_size, void* d_ws, size_t ws_size,
                              hipStream_t stream) {
    const float* pred   = (const float*)d_in[0];
    const int*   labels = (const int*)d_in[1];
    float* row_loss = (float*)d_ws;                       // 8192 floats, written before read

    focal_rows<<<B / 4, 256, 0, stream>>>(pred, labels, row_loss);
    reduce_rows<<<1, 256, 0, stream>>>(row_loss, (float*)d_out);
}